// Round 2
// baseline (13.134 us; speedup 1.0000x reference)
//
#include <hip/hip_runtime.h>
#include <stdint.h>

// RoI max-pool: feature_map (C,H,W) f32, proposals (N,4) f32 -> out (N,C,7,7) f32
//
// One WAVE handles 4 channels of one proposal n (CPW=4, R2: was 8).
// Grid 2048 blocks -> 8 blocks/CU, 32 waves/CU (full occupancy cap) for TLP:
// the R1 experiment showed deepening the per-wave pipeline is null, so the
// residual stall is cross-wave latency coverage, not within-wave depth.
//   - staging: global_load_lds width=16 (2 per channel). LDS dest is linear
//     lane*16B from a wave-uniform base; each buffer is 512 floats so BOTH
//     gll ops (128 float4 span) stay inside their own buffer.
//     Row pitch 24 floats = 6 float4 -> (row,quad) maps linearly to lane.
//     Tail lanes clamp their SOURCE row to rh-1 (duplicate data, never read).
//   - pipeline: 2 buffers, stage ch k+1 before computing ch k (the structure
//     verified in the earlier session). Counted waits from the exact FIFO
//     (2 prologue loads, then per-iter {2 loads, store}): vmcnt {2,3,3,1}.
//   - compute: extents wave-uniform f(rw,rh) (scalarized); uniform branch into
//     E^2-read clamped binmax, branch-free per lane.
// Fallback path (degenerate/oversized region) matches the reference exactly.

constexpr int Cc = 256, Hh = 56, Ww = 56, OUTS = 7;
constexpr int CHW = Hh * Ww;        // 3136
constexpr float SCALEF = 0.0625f;   // 1/16, exact in f32
constexpr float NEGF = -3.4e+38f;
constexpr int RH     = 20;          // max staged rows (this distro: rh<=19)
constexpr int RWQ    = 6;           // float4s per row (24-float window)
constexpr int PITCHF = 24;          // floats per LDS row (= RWQ*4, linear lane map)
constexpr int BUFF   = 512;         // floats per channel buffer (2 gll = 128x16B)
constexpr int WPB    = 4;           // waves per block
constexpr int CPW    = 4;           // channels per wave (R2: halved for 2x TLP)
constexpr int NBUF   = 2;           // double buffer

__device__ __forceinline__ void gll16(const float* g, float* l) {
    __builtin_amdgcn_global_load_lds(
        (const __attribute__((address_space(1))) uint32_t*)g,
        (__attribute__((address_space(3))) uint32_t*)l, 16, 0, 0);
}

template <int E>
__device__ __forceinline__ float binmax(const float* __restrict__ base,
                                        int eh, int ew)
{
    // base = &buf[hs*PITCHF + wofs + ws]; clamped duplicates stay inside the bin
    float m = NEGF;
#pragma unroll
    for (int kr = 0; kr < E; ++kr) {
        const int ro = min(kr, eh) * PITCHF;
#pragma unroll
        for (int kc = 0; kc < E; ++kc)
            m = fmaxf(m, base[ro + min(kc, ew)]);
    }
    return m;
}

__global__ __launch_bounds__(256) void roipool_kernel(
    const float* __restrict__ fm,      // (C,H,W)
    const float* __restrict__ props,   // (N,4)
    float* __restrict__ out)           // (N,C,7,7) flat
{
    __shared__ float lds[WPB][NBUF][BUFF];     // 16 KB/block -> 8 blocks/CU

    const int lane = threadIdx.x & 63;
    const int wid  = __builtin_amdgcn_readfirstlane(threadIdx.x >> 6);
    const int n    = blockIdx.x >> 4;          // 16 channel-groups per n
    const int cg   = blockIdx.x & 15;
    const int c0   = cg * (WPB * CPW) + wid * CPW;

    // box (exact match to jnp.floor(p*0.0625) + clamps); wave-uniform -> SGPR
    const float4 p = reinterpret_cast<const float4*>(props)[n];
    const int x1 = __builtin_amdgcn_readfirstlane(max((int)floorf(p.x * SCALEF), 0));
    const int y1 = __builtin_amdgcn_readfirstlane(max((int)floorf(p.y * SCALEF), 0));
    const int x2 = __builtin_amdgcn_readfirstlane(min((int)floorf(p.z * SCALEF), Ww));
    const int y2 = __builtin_amdgcn_readfirstlane(min((int)floorf(p.w * SCALEF), Hh));
    const int rw = x2 - x1;
    const int rh = y2 - y1;

    float* dst0 = out + ((size_t)n * Cc + c0) * (OUTS * OUTS);
    const float* base0 = fm + (size_t)c0 * CHW;
    const int x1a = x1 & ~3;            // aligned window start

    // fast path: region fits 20x24 window; overread never passes end of fm
    if (rw > 0 && rh > 0 && rw <= 20 && rh <= RH &&
        (y1 + rh < Hh || x1a + RWQ * 4 <= Ww)) {

        // ---- wave-uniform max bin extent (scalar) ----
        int EW = 1, EH = 1;
#pragma unroll
        for (int i = 0; i < 7; ++i) {
            EW = max(EW, ((i + 1) * rw + 6) / 7 - (i * rw) / 7);
            EH = max(EH, ((i + 1) * rh + 6) / 7 - (i * rh) / 7);
        }
        const int E = max(EW, EH);      // in {1..4}

        // ---- per-lane staging source offsets (row-clamped: count-stable) ----
        const int r0 = lane / RWQ,        q0 = lane - r0 * RWQ;
        const int r1 = (lane + 64) / RWQ, q1 = (lane + 64) - r1 * RWQ;
        const int go0 = min(r0, rh - 1) * Ww + q0 * 4;
        const int go1 = min(r1, rh - 1) * Ww + q1 * 4;
        const float* src0 = base0 + y1 * Ww + x1a;    // 16B-aligned

        // ---- per-lane bin coords ----
        const int ow = lane % OUTS;
        const int oh = lane / OUTS;
        const int ws = (ow * rw) / OUTS;
        const int ew = ((ow + 1) * rw + 6) / OUTS - ws - 1;   // extent-1 >= 0
        const int hs = (oh * rh) / OUTS;
        const int eh = ((oh + 1) * rh + 6) / OUTS - hs - 1;
        const int bofs = hs * PITCHF + (x1 - x1a) + ws;

        float* const b0 = &lds[wid][0][0];
        float* const b1 = &lds[wid][1][0];

        // ---- prologue: stage channel 0 ----
        gll16(src0 + go0, b0);
        gll16(src0 + go1, b0 + 256);

#pragma unroll
        for (int k = 0; k < CPW; ++k) {
            const float* buf = (k & 1) ? b1 : b0;
            if (k + 1 < CPW) {                       // stage next channel
                const float* sn = src0 + (k + 1) * CHW;
                float* bn = ((k + 1) & 1) ? b1 : b0;
                gll16(sn + go0, bn);
                gll16(sn + go1, bn + 256);
            }
            // counted waits: exactly drain channel k's 2 loads (in-order vmcnt;
            // FIFO: L0L0 | L1L1 S0 | L2L2 S1 | L3L3 S2 | S3 -> {2,3,3,1})
            if      (k == 0) asm volatile("s_waitcnt vmcnt(2)" ::: "memory");
            else if (k == 1) asm volatile("s_waitcnt vmcnt(3)" ::: "memory");
            else if (k == 2) asm volatile("s_waitcnt vmcnt(3)" ::: "memory");
            else             asm volatile("s_waitcnt vmcnt(1)" ::: "memory");
            __builtin_amdgcn_sched_barrier(0);

            if (lane < OUTS * OUTS) {
                const float* bb = buf + bofs;
                float m;
                if (E <= 2)      m = binmax<2>(bb, eh, ew);
                else if (E == 3) m = binmax<3>(bb, eh, ew);
                else             m = binmax<4>(bb, eh, ew);
                dst0[k * (OUTS * OUTS) + lane] = m;
            }
        }
    } else {
        // ---- general fallback (not hit by this input distribution) ----
        if (lane < OUTS * OUTS) {
            const int ow = lane % OUTS;
            const int oh = lane / OUTS;
            for (int k = 0; k < CPW; ++k) {
                float m = NEGF;
                if (rw > 0 && rh > 0) {
                    const int ws = x1 + (ow * rw) / OUTS;
                    const int we = min(x1 + ((ow + 1) * rw + 6) / OUTS, Ww);
                    const int hs = y1 + (oh * rh) / OUTS;
                    const int he = min(y1 + ((oh + 1) * rh + 6) / OUTS, Hh);
                    const float* b = base0 + (size_t)k * CHW;
                    for (int h = hs; h < he; ++h)
                        for (int w = ws; w < we; ++w)
                            m = fmaxf(m, b[h * Ww + w]);
                }
                dst0[k * (OUTS * OUTS) + lane] = m;
            }
        }
    }
}

extern "C" void kernel_launch(void* const* d_in, const int* in_sizes, int n_in,
                              void* d_out, int out_size, void* d_ws, size_t ws_size,
                              hipStream_t stream)
{
    const float* fm    = (const float*)d_in[0];   // (256,56,56)
    const float* props = (const float*)d_in[1];   // (128,4)
    float* out = (float*)d_out;                   // (128,256,7,7)

    const int N = in_sizes[1] / 4;                 // 128
    const int blocks = N * (Cc / (WPB * CPW));     // 2048 blocks x 256 threads
    roipool_kernel<<<blocks, 256, 0, stream>>>(fm, props, out);
}